// Round 4
// baseline (3962.715 us; speedup 1.0000x reference)
//
#include <hip/hip_runtime.h>

#define B_   128
#define T_   128
#define DIN  64
#define H_   1024
#define NBLK 256
#define NTHR 1024

typedef _Float16 f16;
typedef _Float16 half8 __attribute__((ext_vector_type(8)));
typedef float float4v __attribute__((ext_vector_type(4)));
typedef unsigned uint2v __attribute__((ext_vector_type(2)));
typedef unsigned uint4v __attribute__((ext_vector_type(4)));

// h layout (block-major, exclusive line ownership):
//   h(m, col) at  buf[(col>>2)*512 + m*4 + (col&3)]   (f16 elements)
// Block b writes its 4 columns as ONE contiguous 1KB region [b*512 .. b*512+512).

// LDS layout (16-wave K-split: partial gate buffers A/B per layer):
//  W1s  : f16[34][512]                                  34816 B
//  W2s  : f16[64][512]                                  65536 B
//  Sg1A : float[128][17]   (waves 0-7,  K-half 0)        8704 B
//  Sg1B : float[128][17]   (waves 8-15, K-half 1)        8704 B
//  Sg2A : float[128][17]                                 8704 B
//  Sg2B : float[128][17]                                 8704 B
//  c1,c2: float[512] each                                4096 B
//  bs1,bs2: float[16] each                                128 B   total 139392
#define OFF_W2    34816
#define OFF_SG1A  100352
#define OFF_SG1B  109056
#define OFF_SG2A  117760
#define OFF_SG2B  126464
#define OFF_C1    135168
#define OFF_C2    137216
#define OFF_B1    139264
#define OFF_B2    139328
#define SMEM_BYTES 139392

// Barrier state S (unsigned[2048], 8 KB):
//  S[576 + x*32]   : per-XCD go flag         (polled by <=31 blocks, local line)
//  S[1600 + x]     : per-XCD block count / leader election (preamble only)
//  S[1664 + b]     : per-block arrive flag   (b < 256; written once/phase,
//                    wave-parallel polled by 8 XCD leader blocks)

struct Params {
  const float *x, *Wih1, *Whh1, *bih1, *bhh1, *Wih2, *Whh2, *bih2, *bhh2,
              *Wlin, *blin, *Whio, *bhio;
  const int* fut;
  float* out;
  f16 *x16, *h1a, *h1b, *h2a, *h2b, *ob;
  unsigned *arrive, *rel;
  unsigned *S;
};

__device__ __forceinline__ float sigm(float v) { return 1.f / (1.f + __expf(-v)); }
__device__ __forceinline__ float tanh_(float v) { return 2.f / (1.f + __expf(-2.f * v)) - 1.f; }

__device__ __forceinline__ unsigned get_xcc() {
  unsigned x;
  asm volatile("s_getreg_b32 %0, hwreg(HW_REG_XCC_ID)" : "=s"(x));
  return x & 15u;
}

// ---- slow barrier (preamble only) -----------------------------------------
__device__ __forceinline__ void grid_sync(unsigned* arrive, unsigned* rel, unsigned ph) {
  __syncthreads();
  const int tid = threadIdx.x, bid = blockIdx.x;
  if (bid == 0) {
    if (tid > 0 && tid < NBLK) {
      while (__hip_atomic_load(&arrive[tid], __ATOMIC_RELAXED, __HIP_MEMORY_SCOPE_AGENT) != ph)
        __builtin_amdgcn_s_sleep(8);
    }
    __syncthreads();
    if (tid == 0)
      __hip_atomic_store(rel, ph, __ATOMIC_RELEASE, __HIP_MEMORY_SCOPE_AGENT);
  } else {
    if (tid == 0) {
      __hip_atomic_store(&arrive[bid], ph, __ATOMIC_RELEASE, __HIP_MEMORY_SCOPE_AGENT);
      while (__hip_atomic_load(rel, __ATOMIC_RELAXED, __HIP_MEMORY_SCOPE_AGENT) != ph)
        __builtin_amdgcn_s_sleep(8);
    }
  }
  __syncthreads();
  __builtin_amdgcn_fence(__ATOMIC_ACQUIRE, "agent");
}

// ---- fast barrier v5: flag-array arrive, wave-parallel leader poll --------
// Per phase: every block release-stores S[1664+bid]=ph. The per-XCD leader
// block polls all NBLK flags with 256 threads (one L3 round trip, no RMW
// serialization), does the single per-XCD L2 invalidate, then sets the
// per-XCD go word. Non-leaders poll only their local go word + L1-inv.
__device__ __forceinline__ void fast_sync5(unsigned* S, unsigned x, bool lead, unsigned ph) {
  __syncthreads();
  const int tid = threadIdx.x;
  if (tid == 0)
    __hip_atomic_store(&S[1664 + blockIdx.x], ph, __ATOMIC_RELEASE, __HIP_MEMORY_SCOPE_AGENT);
  if (lead) {
    if (tid < NBLK) {
      while (__hip_atomic_load(&S[1664 + tid], __ATOMIC_RELAXED, __HIP_MEMORY_SCOPE_AGENT) != ph)
        __builtin_amdgcn_s_sleep(1);
    }
    __syncthreads();
    if (tid == 0) {
      asm volatile("buffer_inv sc0 sc1\n\ts_waitcnt vmcnt(0)" ::: "memory");
      __hip_atomic_store(&S[576 + x * 32], ph, __ATOMIC_RELAXED, __HIP_MEMORY_SCOPE_AGENT);
    }
  } else {
    if (tid == 0) {
      while (__hip_atomic_load(&S[576 + x * 32], __ATOMIC_RELAXED, __HIP_MEMORY_SCOPE_AGENT) != ph)
        __builtin_amdgcn_s_sleep(1);
      asm volatile("buffer_inv sc0\n\ts_waitcnt vmcnt(0)" ::: "memory");
    }
  }
  __syncthreads();
}

__global__ void __launch_bounds__(NTHR, 4) lstm_k(Params p) {
  extern __shared__ char smem[];
  f16*   W1s  = (f16*)(smem);
  f16*   W2s  = (f16*)(smem + OFF_W2);
  float* Sg1A = (float*)(smem + OFF_SG1A);
  float* Sg1B = (float*)(smem + OFF_SG1B);
  float* Sg2A = (float*)(smem + OFF_SG2A);
  float* Sg2B = (float*)(smem + OFF_SG2B);
  float* c1   = (float*)(smem + OFF_C1);
  float* c2   = (float*)(smem + OFF_C2);
  float* bs1  = (float*)(smem + OFF_B1);
  float* bs2  = (float*)(smem + OFF_B2);
  __shared__ unsigned s_lead;

  const int tid = threadIdx.x, bid = blockIdx.x;
  const int hb  = bid * 4;
  const int fut = p.fut[0];
  const unsigned xcc = get_xcc();
  unsigned* S = p.S;

  if (bid == 0) {
    for (int i = tid; i < 2048; i += NTHR)
      __hip_atomic_store(&S[i], 0u, __ATOMIC_RELAXED, __HIP_MEMORY_SCOPE_AGENT);
  }

  // ---------------- preamble ------------------------------------------------
  for (int idx = tid; idx < 34 * 512; idx += NTHR) {
    int c = idx >> 9, r = idx & 511;
    int q = r >> 7, colw = (r >> 3) & 15, j = r & 7;
    int k = c * 32 + q * 8 + j;
    int row = (colw >> 2) * H_ + hb + (colw & 3);
    float v = (k < H_) ? p.Whh1[row * H_ + k] : p.Wih1[row * DIN + (k - H_)];
    W1s[idx] = (f16)v;
  }
  for (int idx = tid; idx < 64 * 512; idx += NTHR) {
    int c = idx >> 9, r = idx & 511;
    int q = r >> 7, colw = (r >> 3) & 15, j = r & 7;
    int k = c * 32 + q * 8 + j;
    int row = (colw >> 2) * H_ + hb + (colw & 3);
    float v = (k < H_) ? p.Wih2[row * H_ + k] : p.Whh2[row * H_ + (k - H_)];
    W2s[idx] = (f16)v;
  }
  if (tid < 16) {
    int row = (tid >> 2) * H_ + hb + (tid & 3);
    bs1[tid] = p.bih1[row] + p.bhh1[row];
    bs2[tid] = p.bih2[row] + p.bhh2[row];
  }
  for (int i = tid; i < 512; i += NTHR) { c1[i] = 0.f; c2[i] = 0.f; }
  for (int i = bid * NTHR + tid; i < B_ * T_ * DIN; i += NBLK * NTHR)
    p.x16[i] = (f16)p.x[i];
  for (int i = bid * NTHR + tid; i < B_ * H_; i += NBLK * NTHR) {
    p.h1a[i] = (f16)0.f; p.h1b[i] = (f16)0.f;
    p.h2a[i] = (f16)0.f; p.h2b[i] = (f16)0.f;
  }

  unsigned ph = 1;
  grid_sync(p.arrive, p.rel, ph);
  if (tid == 0) {
    unsigned old = __hip_atomic_fetch_add(&S[1600 + xcc], 1u, __ATOMIC_RELAXED, __HIP_MEMORY_SCOPE_AGENT);
    s_lead = (old == 0u) ? 1u : 0u;   // first arriver on this XCD = leader
  }
  ++ph;
  grid_sync(p.arrive, p.rel, ph);   // includes __syncthreads -> s_lead visible

  const bool lead = (s_lead != 0u);

  auto gsync = [&]() { ++ph; fast_sync5(S, xcc, lead, ph); };

  // ---------- wave geometry: 16 waves = 8 m-tiles x 2 K-halves -------------
  const int lane = tid & 63, wq = tid >> 6;
  const int g  = wq >> 3;        // K-half group (0: j 0..15, 1: j 16..31)
  const int wv = wq & 7;         // m-tile
  const int col = lane & 15, quad = lane >> 4;
  const int m0 = wv * 16 + col;
  const int ko = quad * 8;
  const int jb = g * 16;
  // Bias carried ONLY by K-half 0 (partials are summed in lstm_pw).
  const float b1v = g ? 0.f : bs1[col];
  const float b2v = g ? 0.f : bs2[col];
  const f16* W1f = W1s + lane * 8;
  const f16* W2f = W2s + lane * 8;
  float* S1w = g ? Sg1B : Sg1A;
  float* S2w = g ? Sg2B : Sg2A;
  // block-major h read base: window j pieces at hX + j*4096 + hoff and +512
  const int hoff = quad * 1024 + m0 * 4;

  f16 *h1c = p.h1a, *h1n = p.h1b, *h2c = p.h2a, *h2n = p.h2b;

  // pointwise: idx in [0,512), layer selected by caller
  auto lstm_pw = [&](const float* SgA, const float* SgB, float* cst, f16* hn) {
    int idx = tid & 511;
    int mm = idx >> 2, cc = idx & 3;
    int i0 = mm * 17 + cc;
    float gi = SgA[i0]      + SgB[i0];
    float gf = SgA[i0 + 4]  + SgB[i0 + 4];
    float gg = SgA[i0 + 8]  + SgB[i0 + 8];
    float go = SgA[i0 + 12] + SgB[i0 + 12];
    float cn = sigm(gf) * cst[idx] + sigm(gi) * tanh_(gg);
    cst[idx] = cn;
    f16 hv = (f16)(sigm(go) * tanh_(cn));
    int v = (int)__builtin_bit_cast(unsigned short, hv);
    int base = lane & ~3;
    int v0 = __shfl(v, base, 64),     v1 = __shfl(v, base + 1, 64);
    int v2 = __shfl(v, base + 2, 64), v3 = __shfl(v, base + 3, 64);
    if (cc == 0) {
      unsigned long long pk = (unsigned long long)(unsigned short)v0
        | ((unsigned long long)(unsigned short)v1 << 16)
        | ((unsigned long long)(unsigned short)v2 << 32)
        | ((unsigned long long)(unsigned short)v3 << 48);
      __hip_atomic_store((unsigned long long*)(hn + bid * 512 + mm * 4), pk,
                         __ATOMIC_RELAXED, __HIP_MEMORY_SCOPE_AGENT);
    }
  };

  auto ldwin = [&](const f16* hX, int j) -> half8 {
    const uint2v* q0 = (const uint2v*)(hX + j * 4096 + hoff);
    const uint2v* q1 = (const uint2v*)(hX + j * 4096 + hoff + 512);
    uint2v u0 = *q0, u1 = *q1;
    uint4v u = {u0[0], u0[1], u1[0], u1[1]};
    return __builtin_bit_cast(half8, u);
  };

  // fused phase: gates1(t+1) [l1] and gates2(t) [l2], both keyed on h1c.
  // K-split: group g covers windows jb..jb+15 (and x window 32+g for l1).
  auto phase = [&](bool l1, bool l2, const f16* xp, int xstr) {
    float4v a1 = {b1v, b1v, b1v, b1v};
    float4v a2 = {b2v, b2v, b2v, b2v};

    if (l1) {   // x part (row-major, read-only, cached) — one window per group
      half8 ax = *(const half8*)(xp + m0 * xstr + g * 32 + ko);
      a1 = __builtin_amdgcn_mfma_f32_16x16x32_f16(ax, *(const half8*)(W1f + (32 + g) * 512), a1, 0, 0, 0);
    }
    if (l1 && l2) {
      half8 pf1[4], pf2[4];
      #pragma unroll
      for (int i = 0; i < 4; ++i) { pf1[i] = ldwin(h1c, jb + i); pf2[i] = ldwin(h2c, jb + i); }
      #pragma unroll
      for (int i = 0; i < 16; ++i) {
        int j = jb + i;
        half8 w1 = pf1[i & 3];
        half8 w2 = pf2[i & 3];
        if (i < 12) { pf1[i & 3] = ldwin(h1c, jb + i + 4); pf2[i & 3] = ldwin(h2c, jb + i + 4); }
        a1 = __builtin_amdgcn_mfma_f32_16x16x32_f16(w1, *(const half8*)(W1f + j * 512), a1, 0, 0, 0);
        a2 = __builtin_amdgcn_mfma_f32_16x16x32_f16(w1, *(const half8*)(W2f + j * 512), a2, 0, 0, 0);
        a2 = __builtin_amdgcn_mfma_f32_16x16x32_f16(w2, *(const half8*)(W2f + (32 + j) * 512), a2, 0, 0, 0);
      }
    } else if (l1) {
      half8 pf1[8];
      #pragma unroll
      for (int i = 0; i < 8; ++i) pf1[i] = ldwin(h1c, jb + i);
      #pragma unroll
      for (int i = 0; i < 16; ++i) {
        int j = jb + i;
        half8 w1 = pf1[i & 7];
        if (i < 8) pf1[i & 7] = ldwin(h1c, jb + i + 8);
        a1 = __builtin_amdgcn_mfma_f32_16x16x32_f16(w1, *(const half8*)(W1f + j * 512), a1, 0, 0, 0);
      }
    } else if (l2) {
      half8 pf1[4], pf2[4];
      #pragma unroll
      for (int i = 0; i < 4; ++i) { pf1[i] = ldwin(h1c, jb + i); pf2[i] = ldwin(h2c, jb + i); }
      #pragma unroll
      for (int i = 0; i < 16; ++i) {
        int j = jb + i;
        half8 w1 = pf1[i & 3];
        half8 w2 = pf2[i & 3];
        if (i < 12) { pf1[i & 3] = ldwin(h1c, jb + i + 4); pf2[i & 3] = ldwin(h2c, jb + i + 4); }
        a2 = __builtin_amdgcn_mfma_f32_16x16x32_f16(w1, *(const half8*)(W2f + j * 512), a2, 0, 0, 0);
        a2 = __builtin_amdgcn_mfma_f32_16x16x32_f16(w2, *(const half8*)(W2f + (32 + j) * 512), a2, 0, 0, 0);
      }
    }

    // ---- merged epilogue: partial-gate staging + parallel pointwise ----
    __syncthreads();
    if (l1) {
      #pragma unroll
      for (int r = 0; r < 4; ++r)
        S1w[(wv * 16 + quad * 4 + r) * 17 + col] = a1[r];
    }
    if (l2) {
      #pragma unroll
      for (int r = 0; r < 4; ++r)
        S2w[(wv * 16 + quad * 4 + r) * 17 + col] = a2[r];
    }
    __syncthreads();
    if (tid < 512) {
      if (l1) lstm_pw(Sg1A, Sg1B, c1, h1n);
    } else {
      if (l2) lstm_pw(Sg2A, Sg2B, c2, h2n);
    }
  };

  // small projection: out[m][j] = h2 . W[j] + b[j]  (block-major h2 reads)
  auto out_phase = [&](const float* W, const float* bv, bool wout) {
    if (tid >= 512) return;
    int j = bid & 63, mgp = bid >> 6;
    int rid = tid >> 4, ks = tid & 15;
    int mrow = mgp * 32 + rid;
    const float* wr = W + j * H_ + ks * 64;
    float s = 0.f;
    #pragma unroll
    for (int q = 0; q < 16; ++q) {
      const uint2v* hp = (const uint2v*)(h2c + (ks * 16 + q) * 512 + mrow * 4);
      uint2v u = *hp;
      half8 hv4;
      { uint4v t = {u[0], u[1], 0u, 0u}; hv4 = __builtin_bit_cast(half8, t); }
      s += (float)hv4[0] * wr[q * 4 + 0] + (float)hv4[1] * wr[q * 4 + 1]
         + (float)hv4[2] * wr[q * 4 + 2] + (float)hv4[3] * wr[q * 4 + 3];
    }
    s += __shfl_down(s, 8, 16);
    s += __shfl_down(s, 4, 16);
    s += __shfl_down(s, 2, 16);
    s += __shfl_down(s, 1, 16);
    if (ks == 0) {
      float v = s + bv[j];
      f16 hv = (f16)v;
      __hip_atomic_store((unsigned short*)&p.ob[mrow * 64 + j],
                         __builtin_bit_cast(unsigned short, hv),
                         __ATOMIC_RELAXED, __HIP_MEMORY_SCOPE_AGENT);
      if (wout) p.out[mrow * 64 + j] = v;
    }
  };

  // ---------------- time loop: 129 fused phases ----------------------------
  for (int t = -1; t < T_; ++t) {
    bool l1 = (t + 1 < T_), l2 = (t >= 0);
    phase(l1, l2, p.x16 + (t + 1) * DIN, T_ * DIN);
    gsync();
    if (l1) { f16* tm = h1c; h1c = h1n; h1n = tm; }
    if (l2) { f16* tm = h2c; h2c = h2n; h2n = tm; }
  }
  out_phase(p.Wlin, p.blin, fut == 0);
  gsync();
  for (int f = 0; f < fut; ++f) {
    phase(true, false, p.ob, 64);
    gsync();
    { f16* tm = h1c; h1c = h1n; h1n = tm; }
    phase(false, true, p.ob, 64);
    gsync();
    { f16* tm = h2c; h2c = h2n; h2n = tm; }
    out_phase(p.Whio, p.bhio, f == fut - 1);
    gsync();
  }
}

extern "C" void kernel_launch(void* const* d_in, const int* in_sizes, int n_in,
                              void* d_out, int out_size, void* d_ws, size_t ws_size,
                              hipStream_t stream) {
  char* w = (char*)d_ws;
  auto carve = [&](size_t n) { char* r = w; w += (n + 255) & ~(size_t)255; return r; };

  Params p;
  p.x    = (const float*)d_in[0];
  p.Wih1 = (const float*)d_in[1];
  p.Whh1 = (const float*)d_in[2];
  p.bih1 = (const float*)d_in[3];
  p.bhh1 = (const float*)d_in[4];
  p.Wih2 = (const float*)d_in[5];
  p.Whh2 = (const float*)d_in[6];
  p.bih2 = (const float*)d_in[7];
  p.bhh2 = (const float*)d_in[8];
  p.Wlin = (const float*)d_in[9];
  p.blin = (const float*)d_in[10];
  p.Whio = (const float*)d_in[11];
  p.bhio = (const float*)d_in[12];
  p.fut  = (const int*)d_in[13];
  p.out  = (float*)d_out;

  p.x16 = (f16*)carve((size_t)B_ * T_ * DIN * 2);
  p.h1a = (f16*)carve((size_t)B_ * H_ * 2);
  p.h1b = (f16*)carve((size_t)B_ * H_ * 2);
  p.h2a = (f16*)carve((size_t)B_ * H_ * 2);
  p.h2b = (f16*)carve((size_t)B_ * H_ * 2);
  p.ob  = (f16*)carve((size_t)B_ * 64 * 2);
  p.arrive = (unsigned*)carve(NBLK * sizeof(unsigned));
  p.rel    = (unsigned*)carve(256);
  p.S      = (unsigned*)carve(2048 * sizeof(unsigned));

  (void)hipFuncSetAttribute((const void*)lstm_k,
                            hipFuncAttributeMaxDynamicSharedMemorySize, SMEM_BYTES);
  void* args[] = { &p };
  (void)hipLaunchCooperativeKernel((void*)lstm_k, dim3(NBLK), dim3(NTHR),
                                   args, SMEM_BYTES, stream);
}

// Round 5
// 1889.529 us; speedup vs baseline: 2.0972x; 2.0972x over previous
//
#include <hip/hip_runtime.h>

#define B_   128
#define T_   128
#define DIN  64
#define H_   1024
#define NBLK 256
#define NTHR 1024

typedef _Float16 f16;
typedef _Float16 half8 __attribute__((ext_vector_type(8)));
typedef float float4v __attribute__((ext_vector_type(4)));
typedef unsigned uint2v __attribute__((ext_vector_type(2)));
typedef unsigned uint4v __attribute__((ext_vector_type(4)));

// Pair K-split decomposition:
//   c = bid & 127 : column group (8 h-columns, cols c*8 .. c*8+7)
//   g = bid >> 7  : K-half (h k-range [g*512, g*512+512), x k [g*32,+32))
//   block owns (writes h for) cols c*8+g*4 .. +3  -> write region cb = c*2+g
//   partner bid^128 covers the other K-half; partials exchanged via PB+flag.
//
// h layout (block-major, exclusive line ownership):
//   h(m, col) at  buf[(col>>2)*512 + m*4 + (col&3)]   (f16 elements)
//
// LDS (same 139392 B as proven kernel):
//  W1s : f16[17][2][512]  (16 h1-half windows + 1 x window) x 2 n-tiles  34816 B
//  W2s : f16[32][2][512]  (16 h1-half + 16 h2-half windows) x 2 n-tiles  65536 B
//  Sg1A/Sg1B/Sg2A/Sg2B : float[128][17]  own-nt partials by sub-half     34816 B
//  c1,c2: float[512] each                                                 4096 B
//  bs1,bs2: float[16] each                                                 128 B
#define OFF_W2    34816
#define OFF_SG1A  100352
#define OFF_SG1B  109056
#define OFF_SG2A  117760
#define OFF_SG2B  126464
#define OFF_C1    135168
#define OFF_C2    137216
#define OFF_B1    139264
#define OFF_B2    139328
#define SMEM_BYTES 139392

struct Params {
  const float *x, *Wih1, *Whh1, *bih1, *bhh1, *Wih2, *Whh2, *bih2, *bhh2,
              *Wlin, *blin, *Whio, *bhio;
  const int* fut;
  float* out;
  f16 *x16, *h1a, *h1b, *h2a, *h2b, *ob;
  unsigned *arrive, *rel;
  unsigned *S;
  float* PB;      // partner partials: [c][dg][s][layer][128][16] f32, 8 MB
  unsigned* FL;   // per-block phase flag, one 128B line each: FL[bid*32]
};

__device__ __forceinline__ float sigm(float v) { return 1.f / (1.f + __expf(-v)); }
__device__ __forceinline__ float tanh_(float v) { return 2.f / (1.f + __expf(-2.f * v)) - 1.f; }

__device__ __forceinline__ unsigned get_xcc() {
  unsigned x;
  asm volatile("s_getreg_b32 %0, hwreg(HW_REG_XCC_ID)" : "=s"(x));
  return x & 15u;
}

// ---- slow barrier (preamble only) -----------------------------------------
__device__ __forceinline__ void grid_sync(unsigned* arrive, unsigned* rel, unsigned ph) {
  __syncthreads();
  const int tid = threadIdx.x, bid = blockIdx.x;
  if (bid == 0) {
    if (tid > 0 && tid < NBLK) {
      while (__hip_atomic_load(&arrive[tid], __ATOMIC_RELAXED, __HIP_MEMORY_SCOPE_AGENT) != ph)
        __builtin_amdgcn_s_sleep(8);
    }
    __syncthreads();
    if (tid == 0)
      __hip_atomic_store(rel, ph, __ATOMIC_RELEASE, __HIP_MEMORY_SCOPE_AGENT);
  } else {
    if (tid == 0) {
      __hip_atomic_store(&arrive[bid], ph, __ATOMIC_RELEASE, __HIP_MEMORY_SCOPE_AGENT);
      while (__hip_atomic_load(rel, __ATOMIC_RELAXED, __HIP_MEMORY_SCOPE_AGENT) != ph)
        __builtin_amdgcn_s_sleep(8);
    }
  }
  __syncthreads();
  __builtin_amdgcn_fence(__ATOMIC_ACQUIRE, "agent");
}

// ---- fast barrier v4 (R8-proven, restored verbatim) -----------------------
__device__ __forceinline__ void fast_sync(unsigned* S, unsigned x, unsigned xtotal,
                                          unsigned nxcd, unsigned ph) {
  __syncthreads();
  if (threadIdx.x == 0) {
    unsigned t = __hip_atomic_fetch_add(&S[x * 32], 1u, __ATOMIC_RELAXED, __HIP_MEMORY_SCOPE_AGENT);
    bool leader = (t % xtotal == 0u);
    if ((t + 1u) % xtotal == 0u) {
      unsigned c = __hip_atomic_fetch_add(&S[512], 1u, __ATOMIC_RELAXED, __HIP_MEMORY_SCOPE_AGENT);
      if ((c + 1u) % nxcd == 0u)
        __hip_atomic_store(&S[544], ph, __ATOMIC_RELAXED, __HIP_MEMORY_SCOPE_AGENT);
      asm volatile("buffer_inv sc0 sc1\n\ts_waitcnt vmcnt(0)" ::: "memory");
      __hip_atomic_store(&S[1088 + x * 32], ph, __ATOMIC_RELAXED, __HIP_MEMORY_SCOPE_AGENT);
    }
    if (leader) {
      while (__hip_atomic_load(&S[544], __ATOMIC_RELAXED, __HIP_MEMORY_SCOPE_AGENT) != ph)
        __builtin_amdgcn_s_sleep(1);
      while (__hip_atomic_load(&S[1088 + x * 32], __ATOMIC_RELAXED, __HIP_MEMORY_SCOPE_AGENT) != ph)
        __builtin_amdgcn_s_sleep(1);
      __hip_atomic_store(&S[576 + x * 32], ph, __ATOMIC_RELAXED, __HIP_MEMORY_SCOPE_AGENT);
      asm volatile("buffer_inv sc0\n\ts_waitcnt vmcnt(0)" ::: "memory");
    } else {
      while (__hip_atomic_load(&S[576 + x * 32], __ATOMIC_RELAXED, __HIP_MEMORY_SCOPE_AGENT) != ph)
        __builtin_amdgcn_s_sleep(2);
      asm volatile("buffer_inv sc0\n\ts_waitcnt vmcnt(0)" ::: "memory");
    }
  }
  __syncthreads();
}

__global__ void __launch_bounds__(NTHR, 4) lstm_k(Params p) {
  extern __shared__ char smem[];
  f16*   W1s  = (f16*)(smem);
  f16*   W2s  = (f16*)(smem + OFF_W2);
  float* Sg1A = (float*)(smem + OFF_SG1A);
  float* Sg1B = (float*)(smem + OFF_SG1B);
  float* Sg2A = (float*)(smem + OFF_SG2A);
  float* Sg2B = (float*)(smem + OFF_SG2B);
  float* c1   = (float*)(smem + OFF_C1);
  float* c2   = (float*)(smem + OFF_C2);
  float* bs1  = (float*)(smem + OFF_B1);
  float* bs2  = (float*)(smem + OFF_B2);

  const int tid = threadIdx.x, bid = blockIdx.x;
  const int c   = bid & 127;          // column group (8 cols)
  const int g   = bid >> 7;           // K-half
  const int bidp = bid ^ 128;         // pair partner
  const int cb  = c * 2 + g;          // owned h write region (4 cols)
  const int fut = p.fut[0];
  const unsigned xcc = get_xcc();
  unsigned* S = p.S;

  if (bid == 0) {
    for (int i = tid; i < 2048; i += NTHR)
      __hip_atomic_store(&S[i], 0u, __ATOMIC_RELAXED, __HIP_MEMORY_SCOPE_AGENT);
  }
  // zero pair flags (write-through so remote agent loads see them)
  for (int i = bid * NTHR + tid; i < 256 * 32; i += NBLK * NTHR)
    __hip_atomic_store(&p.FL[i], 0u, __ATOMIC_RELAXED, __HIP_MEMORY_SCOPE_AGENT);

  // ---------------- preamble: weights ---------------------------------------
  // W1s[j][nt][512]: j<16 -> Whh1 k = g*512 + j*32 + quad*8 + jj ; j==16 -> Wih1 k = g*32+...
  for (int idx = tid; idx < 17 * 2 * 512; idx += NTHR) {
    int j2 = idx >> 9, r = idx & 511;
    int j = j2 >> 1, nt = j2 & 1;
    int lane_ = r >> 3, jj = r & 7;
    int q = lane_ >> 4, colw = lane_ & 15;
    int row = (colw >> 2) * H_ + c * 8 + nt * 4 + (colw & 3);
    float v = (j < 16) ? p.Whh1[row * H_ + g * 512 + j * 32 + q * 8 + jj]
                       : p.Wih1[row * DIN + g * 32 + q * 8 + jj];
    W1s[idx] = (f16)v;
  }
  // W2s[j][nt][512]: j<16 -> Wih2 (h1 k-half); j in 16..31 -> Whh2 (h2 k-half)
  for (int idx = tid; idx < 32 * 2 * 512; idx += NTHR) {
    int j2 = idx >> 9, r = idx & 511;
    int j = j2 >> 1, nt = j2 & 1;
    int lane_ = r >> 3, jj = r & 7;
    int q = lane_ >> 4, colw = lane_ & 15;
    int row = (colw >> 2) * H_ + c * 8 + nt * 4 + (colw & 3);
    float v = (j < 16) ? p.Wih2[row * H_ + g * 512 + j * 32 + q * 8 + jj]
                       : p.Whh2[row * H_ + g * 512 + (j - 16) * 32 + q * 8 + jj];
    W2s[idx] = (f16)v;
  }
  if (tid < 16) {   // own 16 gate rows: q = tid>>2, ci = tid&3
    int row = (tid >> 2) * H_ + c * 8 + g * 4 + (tid & 3);
    bs1[tid] = p.bih1[row] + p.bhh1[row];
    bs2[tid] = p.bih2[row] + p.bhh2[row];
  }
  for (int i = tid; i < 512; i += NTHR) { c1[i] = 0.f; c2[i] = 0.f; }
  for (int i = bid * NTHR + tid; i < B_ * T_ * DIN; i += NBLK * NTHR)
    p.x16[i] = (f16)p.x[i];
  for (int i = bid * NTHR + tid; i < B_ * H_; i += NBLK * NTHR) {
    p.h1a[i] = (f16)0.f; p.h1b[i] = (f16)0.f;
    p.h2a[i] = (f16)0.f; p.h2b[i] = (f16)0.f;
  }

  unsigned ph = 1;
  grid_sync(p.arrive, p.rel, ph);
  if (tid == 0)
    __hip_atomic_fetch_add(&S[1600 + xcc], 1u, __ATOMIC_RELAXED, __HIP_MEMORY_SCOPE_AGENT);
  ++ph;
  grid_sync(p.arrive, p.rel, ph);

  unsigned xtotal = __hip_atomic_load(&S[1600 + xcc], __ATOMIC_RELAXED, __HIP_MEMORY_SCOPE_AGENT);
  unsigned nxcd = 0;
  for (int i = 0; i < 16; ++i)
    nxcd += (__hip_atomic_load(&S[1600 + i], __ATOMIC_RELAXED, __HIP_MEMORY_SCOPE_AGENT) != 0u);

  auto gsync = [&]() { ++ph; fast_sync(S, xcc, xtotal, nxcd, ph); };

  // ---------- wave geometry: 16 waves = 8 m-tiles x 2 sub-halves -----------
  const int lane = tid & 63, wq = tid >> 6;
  const int s  = wq >> 3;        // sub-half of the block's 16 windows
  const int wv = wq & 7;         // m-tile
  const int col = lane & 15, quad = lane >> 4;
  const int m0 = wv * 16 + col;
  const int ko = quad * 8;
  const f16* W1f = W1s + lane * 8;
  const f16* W2f = W2s + lane * 8;
  float* S1w = s ? Sg1B : Sg1A;
  float* S2w = s ? Sg2B : Sg2A;
  const int hoff = quad * 1024 + m0 * 4;

  // partner-partial buffer index (floats): [c][dg][s][layer][m][16]
  auto PBidx = [](int cg, int dg, int ss, int ll) {
    return ((((cg * 2 + dg) * 2 + ss) * 2 + ll) * 2048);
  };

  f16 *h1c = p.h1a, *h1n = p.h1b, *h2c = p.h2a, *h2n = p.h2b;
  unsigned pcnt = 0;

  // pointwise for one layer: own LDS partials (both subs) + partner global
  auto lstm_pw = [&](const float* SgA, const float* SgB, float* Pb0, float* Pb1,
                     const float* bsX, float* cst, f16* hn) {
    int idx = tid & 511;
    int mm = idx >> 2, cc = idx & 3;
    int i0 = mm * 17 + cc;
    int pb = mm * 16 + cc;
    float gq[4];
    #pragma unroll
    for (int q = 0; q < 4; ++q) {
      float pv0 = __hip_atomic_load(Pb0 + pb + q * 4, __ATOMIC_RELAXED, __HIP_MEMORY_SCOPE_AGENT);
      float pv1 = __hip_atomic_load(Pb1 + pb + q * 4, __ATOMIC_RELAXED, __HIP_MEMORY_SCOPE_AGENT);
      gq[q] = SgA[i0 + q * 4] + SgB[i0 + q * 4] + pv0 + pv1 + bsX[q * 4 + cc];
    }
    float cn = sigm(gq[1]) * cst[idx] + sigm(gq[0]) * tanh_(gq[2]);
    cst[idx] = cn;
    f16 hv = (f16)(sigm(gq[3]) * tanh_(cn));
    int v = (int)__builtin_bit_cast(unsigned short, hv);
    int base = lane & ~3;
    int v0 = __shfl(v, base, 64),     v1 = __shfl(v, base + 1, 64);
    int v2 = __shfl(v, base + 2, 64), v3 = __shfl(v, base + 3, 64);
    if (cc == 0) {
      unsigned long long pk = (unsigned long long)(unsigned short)v0
        | ((unsigned long long)(unsigned short)v1 << 16)
        | ((unsigned long long)(unsigned short)v2 << 32)
        | ((unsigned long long)(unsigned short)v3 << 48);
      __hip_atomic_store((unsigned long long*)(hn + cb * 512 + mm * 4), pk,
                         __ATOMIC_RELAXED, __HIP_MEMORY_SCOPE_AGENT);
    }
  };

  auto ldwin = [&](const f16* hX, int j) -> half8 {
    const uint2v* q0 = (const uint2v*)(hX + j * 4096 + hoff);
    const uint2v* q1 = (const uint2v*)(hX + j * 4096 + hoff + 512);
    uint2v u0 = *q0, u1 = *q1;
    uint4v u = {u0[0], u0[1], u1[0], u1[1]};
    return __builtin_bit_cast(half8, u);
  };

  // fused phase: gates1(t+1) [l1] and gates2(t) [l2], both keyed on h1c.
  // Block covers its K-half only; partner partials exchanged via PB + flag.
  auto phase = [&](bool l1, bool l2, const f16* xp, int xstr) {
    ++pcnt;
    float4v a1A = {0,0,0,0}, a1B = {0,0,0,0};
    float4v a2A = {0,0,0,0}, a2B = {0,0,0,0};

    if (l1 && s == 0) {   // x window (one per block K-half), sub-half 0 only
      half8 ax = *(const half8*)(xp + m0 * xstr + g * 32 + ko);
      a1A = __builtin_amdgcn_mfma_f32_16x16x32_f16(ax, *(const half8*)(W1f + 32 * 512), a1A, 0, 0, 0);
      a1B = __builtin_amdgcn_mfma_f32_16x16x32_f16(ax, *(const half8*)(W1f + 33 * 512), a1B, 0, 0, 0);
    }
    #pragma unroll
    for (int i = 0; i < 8; ++i) {
      int j = s * 8 + i;          // local window 0..15
      int gw = g * 16 + j;        // global 32-k window of h
      half8 w1 = ldwin(h1c, gw);
      if (l1) {
        a1A = __builtin_amdgcn_mfma_f32_16x16x32_f16(w1, *(const half8*)(W1f + (j * 2) * 512), a1A, 0, 0, 0);
        a1B = __builtin_amdgcn_mfma_f32_16x16x32_f16(w1, *(const half8*)(W1f + (j * 2 + 1) * 512), a1B, 0, 0, 0);
      }
      if (l2) {
        half8 w2 = ldwin(h2c, gw);
        a2A = __builtin_amdgcn_mfma_f32_16x16x32_f16(w1, *(const half8*)(W2f + (j * 2) * 512), a2A, 0, 0, 0);
        a2B = __builtin_amdgcn_mfma_f32_16x16x32_f16(w1, *(const half8*)(W2f + (j * 2 + 1) * 512), a2B, 0, 0, 0);
        a2A = __builtin_amdgcn_mfma_f32_16x16x32_f16(w2, *(const half8*)(W2f + ((16 + j) * 2) * 512), a2A, 0, 0, 0);
        a2B = __builtin_amdgcn_mfma_f32_16x16x32_f16(w2, *(const half8*)(W2f + ((16 + j) * 2 + 1) * 512), a2B, 0, 0, 0);
      }
    }

    // ---- partner partials -> global (write-through), per sub-half ----
    {
      int mb = (wv * 16 + quad * 4) * 16 + col;
      if (l1) {
        float4v pa = g ? a1A : a1B;           // partner n-tile = 1-g
        float* dst = p.PB + PBidx(c, 1 - g, s, 0) + mb;
        #pragma unroll
        for (int r = 0; r < 4; ++r)
          __hip_atomic_store(dst + r * 16, pa[r], __ATOMIC_RELAXED, __HIP_MEMORY_SCOPE_AGENT);
      }
      if (l2) {
        float4v pa = g ? a2A : a2B;
        float* dst = p.PB + PBidx(c, 1 - g, s, 1) + mb;
        #pragma unroll
        for (int r = 0; r < 4; ++r)
          __hip_atomic_store(dst + r * 16, pa[r], __ATOMIC_RELAXED, __HIP_MEMORY_SCOPE_AGENT);
      }
    }
    __syncthreads();   // drains vmcnt -> all partial stores at coherence point
    if (tid == 0)
      __hip_atomic_store(&p.FL[bid * 32], pcnt, __ATOMIC_RELEASE, __HIP_MEMORY_SCOPE_AGENT);

    // ---- own-nt partials -> LDS staging ----
    if (l1) {
      float4v oa = g ? a1B : a1A;             // own n-tile = g
      #pragma unroll
      for (int r = 0; r < 4; ++r)
        S1w[(wv * 16 + quad * 4 + r) * 17 + col] = oa[r];
    }
    if (l2) {
      float4v oa = g ? a2B : a2A;
      #pragma unroll
      for (int r = 0; r < 4; ++r)
        S2w[(wv * 16 + quad * 4 + r) * 17 + col] = oa[r];
    }
    __syncthreads();

    // ---- wait for partner's partials, then pointwise ----
    while (__hip_atomic_load(&p.FL[bidp * 32], __ATOMIC_RELAXED, __HIP_MEMORY_SCOPE_AGENT) < pcnt)
      __builtin_amdgcn_s_sleep(1);

    if (tid < 512) {
      if (l1) lstm_pw(Sg1A, Sg1B,
                      p.PB + PBidx(c, g, 0, 0), p.PB + PBidx(c, g, 1, 0),
                      bs1, c1, h1n);
    } else {
      if (l2) lstm_pw(Sg2A, Sg2B,
                      p.PB + PBidx(c, g, 0, 1), p.PB + PBidx(c, g, 1, 1),
                      bs2, c2, h2n);
    }
  };

  // small projection: out[m][j] = h2 . W[j] + b[j]  (block-major h2 reads)
  auto out_phase = [&](const float* W, const float* bv, bool wout) {
    if (tid >= 512) return;
    int j = bid & 63, mgp = bid >> 6;
    int rid = tid >> 4, ks = tid & 15;
    int mrow = mgp * 32 + rid;
    const float* wr = W + j * H_ + ks * 64;
    float sacc = 0.f;
    #pragma unroll
    for (int q = 0; q < 16; ++q) {
      const uint2v* hp = (const uint2v*)(h2c + (ks * 16 + q) * 512 + mrow * 4);
      uint2v u = *hp;
      half8 hv4;
      { uint4v t = {u[0], u[1], 0u, 0u}; hv4 = __builtin_bit_cast(half8, t); }
      sacc += (float)hv4[0] * wr[q * 4 + 0] + (float)hv4[1] * wr[q * 4 + 1]
            + (float)hv4[2] * wr[q * 4 + 2] + (float)hv4[3] * wr[q * 4 + 3];
    }
    sacc += __shfl_down(sacc, 8, 16);
    sacc += __shfl_down(sacc, 4, 16);
    sacc += __shfl_down(sacc, 2, 16);
    sacc += __shfl_down(sacc, 1, 16);
    if (ks == 0) {
      float v = sacc + bv[j];
      f16 hv = (f16)v;
      __hip_atomic_store((unsigned short*)&p.ob[mrow * 64 + j],
                         __builtin_bit_cast(unsigned short, hv),
                         __ATOMIC_RELAXED, __HIP_MEMORY_SCOPE_AGENT);
      if (wout) p.out[mrow * 64 + j] = v;
    }
  };

  // ---------------- time loop: 129 fused phases ----------------------------
  for (int t = -1; t < T_; ++t) {
    bool l1 = (t + 1 < T_), l2 = (t >= 0);
    phase(l1, l2, p.x16 + (t + 1) * DIN, T_ * DIN);
    gsync();
    if (l1) { f16* tm = h1c; h1c = h1n; h1n = tm; }
    if (l2) { f16* tm = h2c; h2c = h2n; h2n = tm; }
  }
  out_phase(p.Wlin, p.blin, fut == 0);
  gsync();
  for (int f = 0; f < fut; ++f) {
    phase(true, false, p.ob, 64);
    gsync();
    { f16* tm = h1c; h1c = h1n; h1n = tm; }
    phase(false, true, p.ob, 64);
    gsync();
    { f16* tm = h2c; h2c = h2n; h2n = tm; }
    out_phase(p.Whio, p.bhio, f == fut - 1);
    gsync();
  }
}

extern "C" void kernel_launch(void* const* d_in, const int* in_sizes, int n_in,
                              void* d_out, int out_size, void* d_ws, size_t ws_size,
                              hipStream_t stream) {
  char* w = (char*)d_ws;
  auto carve = [&](size_t n) { char* r = w; w += (n + 255) & ~(size_t)255; return r; };

  Params p;
  p.x    = (const float*)d_in[0];
  p.Wih1 = (const float*)d_in[1];
  p.Whh1 = (const float*)d_in[2];
  p.bih1 = (const float*)d_in[3];
  p.bhh1 = (const float*)d_in[4];
  p.Wih2 = (const float*)d_in[5];
  p.Whh2 = (const float*)d_in[6];
  p.bih2 = (const float*)d_in[7];
  p.bhh2 = (const float*)d_in[8];
  p.Wlin = (const float*)d_in[9];
  p.blin = (const float*)d_in[10];
  p.Whio = (const float*)d_in[11];
  p.bhio = (const float*)d_in[12];
  p.fut  = (const int*)d_in[13];
  p.out  = (float*)d_out;

  p.x16 = (f16*)carve((size_t)B_ * T_ * DIN * 2);
  p.h1a = (f16*)carve((size_t)B_ * H_ * 2);
  p.h1b = (f16*)carve((size_t)B_ * H_ * 2);
  p.h2a = (f16*)carve((size_t)B_ * H_ * 2);
  p.h2b = (f16*)carve((size_t)B_ * H_ * 2);
  p.ob  = (f16*)carve((size_t)B_ * 64 * 2);
  p.arrive = (unsigned*)carve(NBLK * sizeof(unsigned));
  p.rel    = (unsigned*)carve(256);
  p.S      = (unsigned*)carve(2048 * sizeof(unsigned));
  p.PB     = (float*)carve((size_t)128 * 2 * 2 * 2 * 2048 * sizeof(float));  // 8 MB
  p.FL     = (unsigned*)carve((size_t)256 * 32 * sizeof(unsigned));          // 32 KB

  (void)hipFuncSetAttribute((const void*)lstm_k,
                            hipFuncAttributeMaxDynamicSharedMemorySize, SMEM_BYTES);
  void* args[] = { &p };
  (void)hipLaunchCooperativeKernel((void*)lstm_k, dim3(NBLK), dim3(NTHR),
                                   args, SMEM_BYTES, stream);
}

// Round 6
// 1856.828 us; speedup vs baseline: 2.1341x; 1.0176x over previous
//
#include <hip/hip_runtime.h>

#define B_   128
#define T_   128
#define DIN  64
#define H_   1024
#define NBLK 256
#define NTHR 1024

typedef _Float16 f16;
typedef _Float16 half8 __attribute__((ext_vector_type(8)));
typedef float float4v __attribute__((ext_vector_type(4)));
typedef unsigned uint2v __attribute__((ext_vector_type(2)));
typedef unsigned uint4v __attribute__((ext_vector_type(4)));
typedef unsigned long long u64;

// Pair K-split decomposition (R5, unchanged):
//   c = bid & 127 : column group; g = bid >> 7 : K-half; partner = bid^128.
//   block owns h write region cb = c*2+g (4 cols, contiguous 1KB).
//
// NEW (R6): NO cache invalidates anywhere. All cross-phase-mutable data
// (h buffers, PB partials, FL flags, ob) are accessed with SYSTEM-scope
// (sc0 sc1, cache-bypassing) atomics -> always coherent at the IF point.
// The global barrier is retained for skew bounding but is pure sync.
#define OFF_W2    34816
#define OFF_SG1A  100352
#define OFF_SG1B  109056
#define OFF_SG2A  117760
#define OFF_SG2B  126464
#define OFF_C1    135168
#define OFF_C2    137216
#define OFF_B1    139264
#define OFF_B2    139328
#define SMEM_BYTES 139392

struct Params {
  const float *x, *Wih1, *Whh1, *bih1, *bhh1, *Wih2, *Whh2, *bih2, *bhh2,
              *Wlin, *blin, *Whio, *bhio;
  const int* fut;
  float* out;
  f16 *x16, *h1a, *h1b, *h2a, *h2b, *ob;
  unsigned *arrive, *rel;
  unsigned *S;
  float* PB;      // partner partials: [c][dg][s][layer][128][16] f32, 8 MB
  unsigned* FL;   // per-block phase flag, one 128B line each: FL[bid*32]
};

__device__ __forceinline__ float sigm(float v) { return 1.f / (1.f + __expf(-v)); }
__device__ __forceinline__ float tanh_(float v) { return 2.f / (1.f + __expf(-2.f * v)) - 1.f; }

__device__ __forceinline__ unsigned get_xcc() {
  unsigned x;
  asm volatile("s_getreg_b32 %0, hwreg(HW_REG_XCC_ID)" : "=s"(x));
  return x & 15u;
}

__device__ __forceinline__ u64 sysld(const void* p_) {
  return __hip_atomic_load((const u64*)p_, __ATOMIC_RELAXED, __HIP_MEMORY_SCOPE_SYSTEM);
}
__device__ __forceinline__ void sysst(void* p_, u64 v) {
  __hip_atomic_store((u64*)p_, v, __ATOMIC_RELAXED, __HIP_MEMORY_SCOPE_SYSTEM);
}

// ---- slow barrier (preamble only) -----------------------------------------
__device__ __forceinline__ void grid_sync(unsigned* arrive, unsigned* rel, unsigned ph) {
  __syncthreads();
  const int tid = threadIdx.x, bid = blockIdx.x;
  if (bid == 0) {
    if (tid > 0 && tid < NBLK) {
      while (__hip_atomic_load(&arrive[tid], __ATOMIC_RELAXED, __HIP_MEMORY_SCOPE_AGENT) != ph)
        __builtin_amdgcn_s_sleep(8);
    }
    __syncthreads();
    if (tid == 0)
      __hip_atomic_store(rel, ph, __ATOMIC_RELEASE, __HIP_MEMORY_SCOPE_AGENT);
  } else {
    if (tid == 0) {
      __hip_atomic_store(&arrive[bid], ph, __ATOMIC_RELEASE, __HIP_MEMORY_SCOPE_AGENT);
      while (__hip_atomic_load(rel, __ATOMIC_RELAXED, __HIP_MEMORY_SCOPE_AGENT) != ph)
        __builtin_amdgcn_s_sleep(8);
    }
  }
  __syncthreads();
  __builtin_amdgcn_fence(__ATOMIC_ACQUIRE, "agent");
}

// ---- fast barrier v6: v4 ticket structure, NO invalidates -----------------
__device__ __forceinline__ void fast_sync(unsigned* S, unsigned x, unsigned xtotal,
                                          unsigned nxcd, unsigned ph) {
  __syncthreads();
  if (threadIdx.x == 0) {
    unsigned t = __hip_atomic_fetch_add(&S[x * 32], 1u, __ATOMIC_RELAXED, __HIP_MEMORY_SCOPE_AGENT);
    bool leader = (t % xtotal == 0u);
    if ((t + 1u) % xtotal == 0u) {
      unsigned c = __hip_atomic_fetch_add(&S[512], 1u, __ATOMIC_RELAXED, __HIP_MEMORY_SCOPE_AGENT);
      if ((c + 1u) % nxcd == 0u)
        __hip_atomic_store(&S[544], ph, __ATOMIC_RELAXED, __HIP_MEMORY_SCOPE_AGENT);
      __hip_atomic_store(&S[1088 + x * 32], ph, __ATOMIC_RELAXED, __HIP_MEMORY_SCOPE_AGENT);
    }
    if (leader) {
      while (__hip_atomic_load(&S[544], __ATOMIC_RELAXED, __HIP_MEMORY_SCOPE_AGENT) != ph)
        __builtin_amdgcn_s_sleep(1);
      while (__hip_atomic_load(&S[1088 + x * 32], __ATOMIC_RELAXED, __HIP_MEMORY_SCOPE_AGENT) != ph)
        __builtin_amdgcn_s_sleep(1);
      __hip_atomic_store(&S[576 + x * 32], ph, __ATOMIC_RELAXED, __HIP_MEMORY_SCOPE_AGENT);
    } else {
      while (__hip_atomic_load(&S[576 + x * 32], __ATOMIC_RELAXED, __HIP_MEMORY_SCOPE_AGENT) != ph)
        __builtin_amdgcn_s_sleep(2);
    }
  }
  __syncthreads();
}

__global__ void __launch_bounds__(NTHR, 4) lstm_k(Params p) {
  extern __shared__ char smem[];
  f16*   W1s  = (f16*)(smem);
  f16*   W2s  = (f16*)(smem + OFF_W2);
  float* Sg1A = (float*)(smem + OFF_SG1A);
  float* Sg1B = (float*)(smem + OFF_SG1B);
  float* Sg2A = (float*)(smem + OFF_SG2A);
  float* Sg2B = (float*)(smem + OFF_SG2B);
  float* c1   = (float*)(smem + OFF_C1);
  float* c2   = (float*)(smem + OFF_C2);
  float* bs1  = (float*)(smem + OFF_B1);
  float* bs2  = (float*)(smem + OFF_B2);

  const int tid = threadIdx.x, bid = blockIdx.x;
  const int c   = bid & 127;          // column group (8 cols)
  const int g   = bid >> 7;           // K-half
  const int bidp = bid ^ 128;         // pair partner
  const int cb  = c * 2 + g;          // owned h write region (4 cols)
  const int fut = p.fut[0];
  const unsigned xcc = get_xcc();
  unsigned* S = p.S;

  if (bid == 0) {
    for (int i = tid; i < 2048; i += NTHR)
      __hip_atomic_store(&S[i], 0u, __ATOMIC_RELAXED, __HIP_MEMORY_SCOPE_AGENT);
  }
  // zero pair flags (system scope -> visible to bypass polls)
  for (int i = bid * NTHR + tid; i < 256 * 32 / 2; i += NBLK * NTHR)
    sysst(&p.FL[i * 2], 0ull);

  // ---------------- preamble: weights ---------------------------------------
  for (int idx = tid; idx < 17 * 2 * 512; idx += NTHR) {
    int j2 = idx >> 9, r = idx & 511;
    int j = j2 >> 1, nt = j2 & 1;
    int lane_ = r >> 3, jj = r & 7;
    int q = lane_ >> 4, colw = lane_ & 15;
    int row = (colw >> 2) * H_ + c * 8 + nt * 4 + (colw & 3);
    float v = (j < 16) ? p.Whh1[row * H_ + g * 512 + j * 32 + q * 8 + jj]
                       : p.Wih1[row * DIN + g * 32 + q * 8 + jj];
    W1s[idx] = (f16)v;
  }
  for (int idx = tid; idx < 32 * 2 * 512; idx += NTHR) {
    int j2 = idx >> 9, r = idx & 511;
    int j = j2 >> 1, nt = j2 & 1;
    int lane_ = r >> 3, jj = r & 7;
    int q = lane_ >> 4, colw = lane_ & 15;
    int row = (colw >> 2) * H_ + c * 8 + nt * 4 + (colw & 3);
    float v = (j < 16) ? p.Wih2[row * H_ + g * 512 + j * 32 + q * 8 + jj]
                       : p.Whh2[row * H_ + g * 512 + (j - 16) * 32 + q * 8 + jj];
    W2s[idx] = (f16)v;
  }
  if (tid < 16) {
    int row = (tid >> 2) * H_ + c * 8 + g * 4 + (tid & 3);
    bs1[tid] = p.bih1[row] + p.bhh1[row];
    bs2[tid] = p.bih2[row] + p.bhh2[row];
  }
  for (int i = tid; i < 512; i += NTHR) { c1[i] = 0.f; c2[i] = 0.f; }
  for (int i = bid * NTHR + tid; i < B_ * T_ * DIN; i += NBLK * NTHR)
    p.x16[i] = (f16)p.x[i];
  // h zero-init via system stores (visible to bypass reads)
  for (int i = bid * NTHR + tid; i < B_ * H_ / 4; i += NBLK * NTHR) {
    sysst((u64*)p.h1a + i, 0ull); sysst((u64*)p.h1b + i, 0ull);
    sysst((u64*)p.h2a + i, 0ull); sysst((u64*)p.h2b + i, 0ull);
  }

  unsigned ph = 1;
  grid_sync(p.arrive, p.rel, ph);
  if (tid == 0)
    __hip_atomic_fetch_add(&S[1600 + xcc], 1u, __ATOMIC_RELAXED, __HIP_MEMORY_SCOPE_AGENT);
  ++ph;
  grid_sync(p.arrive, p.rel, ph);

  unsigned xtotal = __hip_atomic_load(&S[1600 + xcc], __ATOMIC_RELAXED, __HIP_MEMORY_SCOPE_AGENT);
  unsigned nxcd = 0;
  for (int i = 0; i < 16; ++i)
    nxcd += (__hip_atomic_load(&S[1600 + i], __ATOMIC_RELAXED, __HIP_MEMORY_SCOPE_AGENT) != 0u);

  auto gsync = [&]() { ++ph; fast_sync(S, xcc, xtotal, nxcd, ph); };

  // ---------- wave geometry: 16 waves = 8 m-tiles x 2 sub-halves -----------
  const int lane = tid & 63, wq = tid >> 6;
  const int s  = wq >> 3;
  const int wv = wq & 7;
  const int col = lane & 15, quad = lane >> 4;
  const int m0 = wv * 16 + col;
  const int ko = quad * 8;
  const f16* W1f = W1s + lane * 8;
  const f16* W2f = W2s + lane * 8;
  float* S1w = s ? Sg1B : Sg1A;
  float* S2w = s ? Sg2B : Sg2A;
  const int hoff = quad * 1024 + m0 * 4;

  auto PBidx = [](int cg, int dg, int ss, int ll) {
    return ((((cg * 2 + dg) * 2 + ss) * 2 + ll) * 2048);
  };

  f16 *h1c = p.h1a, *h1n = p.h1b, *h2c = p.h2a, *h2n = p.h2b;
  unsigned pcnt = 0;

  // pointwise: own LDS partials (both subs) + partner global (bypass reads)
  auto lstm_pw = [&](const float* SgA, const float* SgB, float* Pb0, float* Pb1,
                     const float* bsX, float* cst, f16* hn) {
    int idx = tid & 511;
    int mm = idx >> 2, cc = idx & 3;
    int i0 = mm * 17 + cc;
    int pb = mm * 16 + cc;
    float gq[4];
    #pragma unroll
    for (int q = 0; q < 4; ++q) {
      float pv0 = __hip_atomic_load(Pb0 + pb + q * 4, __ATOMIC_RELAXED, __HIP_MEMORY_SCOPE_SYSTEM);
      float pv1 = __hip_atomic_load(Pb1 + pb + q * 4, __ATOMIC_RELAXED, __HIP_MEMORY_SCOPE_SYSTEM);
      gq[q] = SgA[i0 + q * 4] + SgB[i0 + q * 4] + pv0 + pv1 + bsX[q * 4 + cc];
    }
    float cn = sigm(gq[1]) * cst[idx] + sigm(gq[0]) * tanh_(gq[2]);
    cst[idx] = cn;
    f16 hv = (f16)(sigm(gq[3]) * tanh_(cn));
    int v = (int)__builtin_bit_cast(unsigned short, hv);
    int base = lane & ~3;
    int v0 = __shfl(v, base, 64),     v1 = __shfl(v, base + 1, 64);
    int v2 = __shfl(v, base + 2, 64), v3 = __shfl(v, base + 3, 64);
    if (cc == 0) {
      u64 pk = (u64)(unsigned short)v0
        | ((u64)(unsigned short)v1 << 16)
        | ((u64)(unsigned short)v2 << 32)
        | ((u64)(unsigned short)v3 << 48);
      sysst(hn + cb * 512 + mm * 4, pk);
    }
  };

  // bypass (system-scope) 16B h window read
  auto ldwin = [&](const f16* hX, int j) -> half8 {
    u64 u0 = sysld(hX + j * 4096 + hoff);
    u64 u1 = sysld(hX + j * 4096 + hoff + 512);
    uint2v a0 = __builtin_bit_cast(uint2v, u0);
    uint2v a1 = __builtin_bit_cast(uint2v, u1);
    uint4v u = {a0[0], a0[1], a1[0], a1[1]};
    return __builtin_bit_cast(half8, u);
  };

  // fused phase; xb=true -> x input is ob (mutable, needs bypass reads)
  auto phase = [&](bool l1, bool l2, const f16* xp, int xstr, bool xb) {
    ++pcnt;
    float4v a1A = {0,0,0,0}, a1B = {0,0,0,0};
    float4v a2A = {0,0,0,0}, a2B = {0,0,0,0};

    if (l1 && s == 0) {
      half8 ax;
      if (xb) {
        u64 u0 = sysld(xp + m0 * xstr + g * 32 + ko);
        u64 u1 = sysld(xp + m0 * xstr + g * 32 + ko + 4);
        uint2v a0 = __builtin_bit_cast(uint2v, u0);
        uint2v a1v = __builtin_bit_cast(uint2v, u1);
        uint4v u = {a0[0], a0[1], a1v[0], a1v[1]};
        ax = __builtin_bit_cast(half8, u);
      } else {
        ax = *(const half8*)(xp + m0 * xstr + g * 32 + ko);
      }
      a1A = __builtin_amdgcn_mfma_f32_16x16x32_f16(ax, *(const half8*)(W1f + 32 * 512), a1A, 0, 0, 0);
      a1B = __builtin_amdgcn_mfma_f32_16x16x32_f16(ax, *(const half8*)(W1f + 33 * 512), a1B, 0, 0, 0);
    }
    #pragma unroll
    for (int i = 0; i < 8; ++i) {
      int j = s * 8 + i;
      int gw = g * 16 + j;
      half8 w1 = ldwin(h1c, gw);
      if (l1) {
        a1A = __builtin_amdgcn_mfma_f32_16x16x32_f16(w1, *(const half8*)(W1f + (j * 2) * 512), a1A, 0, 0, 0);
        a1B = __builtin_amdgcn_mfma_f32_16x16x32_f16(w1, *(const half8*)(W1f + (j * 2 + 1) * 512), a1B, 0, 0, 0);
      }
      if (l2) {
        half8 w2 = ldwin(h2c, gw);
        a2A = __builtin_amdgcn_mfma_f32_16x16x32_f16(w1, *(const half8*)(W2f + (j * 2) * 512), a2A, 0, 0, 0);
        a2B = __builtin_amdgcn_mfma_f32_16x16x32_f16(w1, *(const half8*)(W2f + (j * 2 + 1) * 512), a2B, 0, 0, 0);
        a2A = __builtin_amdgcn_mfma_f32_16x16x32_f16(w2, *(const half8*)(W2f + ((16 + j) * 2) * 512), a2A, 0, 0, 0);
        a2B = __builtin_amdgcn_mfma_f32_16x16x32_f16(w2, *(const half8*)(W2f + ((16 + j) * 2 + 1) * 512), a2B, 0, 0, 0);
      }
    }

    // ---- partner partials -> global (system write-through) ----
    {
      int mb = (wv * 16 + quad * 4) * 16 + col;
      if (l1) {
        float4v pa = g ? a1A : a1B;
        float* dst = p.PB + PBidx(c, 1 - g, s, 0) + mb;
        #pragma unroll
        for (int r = 0; r < 4; ++r)
          __hip_atomic_store(dst + r * 16, pa[r], __ATOMIC_RELAXED, __HIP_MEMORY_SCOPE_SYSTEM);
      }
      if (l2) {
        float4v pa = g ? a2A : a2B;
        float* dst = p.PB + PBidx(c, 1 - g, s, 1) + mb;
        #pragma unroll
        for (int r = 0; r < 4; ++r)
          __hip_atomic_store(dst + r * 16, pa[r], __ATOMIC_RELAXED, __HIP_MEMORY_SCOPE_SYSTEM);
      }
    }
    __syncthreads();   // drains vmcnt -> all partial stores visible
    if (tid == 0)
      __hip_atomic_store(&p.FL[bid * 32], pcnt, __ATOMIC_RELEASE, __HIP_MEMORY_SCOPE_SYSTEM);

    // ---- own-nt partials -> LDS staging ----
    if (l1) {
      float4v oa = g ? a1B : a1A;
      #pragma unroll
      for (int r = 0; r < 4; ++r)
        S1w[(wv * 16 + quad * 4 + r) * 17 + col] = oa[r];
    }
    if (l2) {
      float4v oa = g ? a2B : a2A;
      #pragma unroll
      for (int r = 0; r < 4; ++r)
        S2w[(wv * 16 + quad * 4 + r) * 17 + col] = oa[r];
    }
    __syncthreads();

    // ---- wait for partner's partials (bypass poll), then pointwise ----
    while (__hip_atomic_load(&p.FL[bidp * 32], __ATOMIC_RELAXED, __HIP_MEMORY_SCOPE_SYSTEM) < pcnt)
      __builtin_amdgcn_s_sleep(1);

    if (tid < 512) {
      if (l1) lstm_pw(Sg1A, Sg1B,
                      p.PB + PBidx(c, g, 0, 0), p.PB + PBidx(c, g, 1, 0),
                      bs1, c1, h1n);
    } else {
      if (l2) lstm_pw(Sg2A, Sg2B,
                      p.PB + PBidx(c, g, 0, 1), p.PB + PBidx(c, g, 1, 1),
                      bs2, c2, h2n);
    }
  };

  // small projection: out[m][j] = h2 . W[j] + b[j]  (bypass h2 reads)
  auto out_phase = [&](const float* W, const float* bv, bool wout) {
    if (tid >= 512) return;
    int j = bid & 63, mgp = bid >> 6;
    int rid = tid >> 4, ks = tid & 15;
    int mrow = mgp * 32 + rid;
    const float* wr = W + j * H_ + ks * 64;
    float sacc = 0.f;
    #pragma unroll
    for (int q = 0; q < 16; ++q) {
      u64 uv = sysld(h2c + (ks * 16 + q) * 512 + mrow * 4);
      uint2v uu = __builtin_bit_cast(uint2v, uv);
      half8 hv4;
      { uint4v t = {uu[0], uu[1], 0u, 0u}; hv4 = __builtin_bit_cast(half8, t); }
      sacc += (float)hv4[0] * wr[q * 4 + 0] + (float)hv4[1] * wr[q * 4 + 1]
            + (float)hv4[2] * wr[q * 4 + 2] + (float)hv4[3] * wr[q * 4 + 3];
    }
    sacc += __shfl_down(sacc, 8, 16);
    sacc += __shfl_down(sacc, 4, 16);
    sacc += __shfl_down(sacc, 2, 16);
    sacc += __shfl_down(sacc, 1, 16);
    if (ks == 0) {
      float v = sacc + bv[j];
      f16 hv = (f16)v;
      unsigned short hb16 = __builtin_bit_cast(unsigned short, hv);
      __hip_atomic_store((unsigned short*)&p.ob[mrow * 64 + j], hb16,
                         __ATOMIC_RELAXED, __HIP_MEMORY_SCOPE_SYSTEM);
      if (wout) p.out[mrow * 64 + j] = v;
    }
  };

  // ---------------- time loop: 129 fused phases ----------------------------
  for (int t = -1; t < T_; ++t) {
    bool l1 = (t + 1 < T_), l2 = (t >= 0);
    phase(l1, l2, p.x16 + (t + 1) * DIN, T_ * DIN, false);
    gsync();
    if (l1) { f16* tm = h1c; h1c = h1n; h1n = tm; }
    if (l2) { f16* tm = h2c; h2c = h2n; h2n = tm; }
  }
  out_phase(p.Wlin, p.blin, fut == 0);
  gsync();
  for (int f = 0; f < fut; ++f) {
    phase(true, false, p.ob, 64, true);
    gsync();
    { f16* tm = h1c; h1c = h1n; h1n = tm; }
    phase(false, true, p.ob, 64, true);
    gsync();
    { f16* tm = h2c; h2c = h2n; h2n = tm; }
    out_phase(p.Whio, p.bhio, f == fut - 1);
    gsync();
  }
}

extern "C" void kernel_launch(void* const* d_in, const int* in_sizes, int n_in,
                              void* d_out, int out_size, void* d_ws, size_t ws_size,
                              hipStream_t stream) {
  char* w = (char*)d_ws;
  auto carve = [&](size_t n) { char* r = w; w += (n + 255) & ~(size_t)255; return r; };

  Params p;
  p.x    = (const float*)d_in[0];
  p.Wih1 = (const float*)d_in[1];
  p.Whh1 = (const float*)d_in[2];
  p.bih1 = (const float*)d_in[3];
  p.bhh1 = (const float*)d_in[4];
  p.Wih2 = (const float*)d_in[5];
  p.Whh2 = (const float*)d_in[6];
  p.bih2 = (const float*)d_in[7];
  p.bhh2 = (const float*)d_in[8];
  p.Wlin = (const float*)d_in[9];
  p.blin = (const float*)d_in[10];
  p.Whio = (const float*)d_in[11];
  p.bhio = (const float*)d_in[12];
  p.fut  = (const int*)d_in[13];
  p.out  = (float*)d_out;

  p.x16 = (f16*)carve((size_t)B_ * T_ * DIN * 2);
  p.h1a = (f16*)carve((size_t)B_ * H_ * 2);
  p.h1b = (f16*)carve((size_t)B_ * H_ * 2);
  p.h2a = (f16*)carve((size_t)B_ * H_ * 2);
  p.h2b = (f16*)carve((size_t)B_ * H_ * 2);
  p.ob  = (f16*)carve((size_t)B_ * 64 * 2);
  p.arrive = (unsigned*)carve(NBLK * sizeof(unsigned));
  p.rel    = (unsigned*)carve(256);
  p.S      = (unsigned*)carve(2048 * sizeof(unsigned));
  p.PB     = (float*)carve((size_t)128 * 2 * 2 * 2 * 2048 * sizeof(float));  // 8 MB
  p.FL     = (unsigned*)carve((size_t)256 * 32 * sizeof(unsigned));          // 32 KB

  (void)hipFuncSetAttribute((const void*)lstm_k,
                            hipFuncAttributeMaxDynamicSharedMemorySize, SMEM_BYTES);
  void* args[] = { &p };
  (void)hipLaunchCooperativeKernel((void*)lstm_k, dim3(NBLK), dim3(NTHR),
                                   args, SMEM_BYTES, stream);
}